// Round 1
// baseline (450.114 us; speedup 1.0000x reference)
//
#include <hip/hip_runtime.h>

#define NN 4096
#define BB 32
#define UU 64
#define MAXNNZ 96

typedef float f32x4 __attribute__((ext_vector_type(4)));
typedef short bf16x8 __attribute__((ext_vector_type(8)));
typedef unsigned short us8 __attribute__((ext_vector_type(8)));
typedef unsigned short us4 __attribute__((ext_vector_type(4)));

__device__ __forceinline__ float bf2f(unsigned short u) {
    return __uint_as_float(((unsigned)u) << 16);
}
__device__ __forceinline__ unsigned short f2bf(float f) {
    unsigned x = __float_as_uint(f);
    x += 0x7fffu + ((x >> 16) & 1u);
    return (unsigned short)(x >> 16);
}

// ---------------------------------------------------------------------------
// K1: dense support (4096x4096 f32) -> padded ELL (cols int32, vals f32, cnt)
// one wave per row; deterministic ballot/prefix compaction.
// ---------------------------------------------------------------------------
__global__ void build_ell(const float* __restrict__ sup, int* __restrict__ cols,
                          float* __restrict__ vals, int* __restrict__ cnt) {
    int row  = blockIdx.x * 4 + (threadIdx.x >> 6);
    int lane = threadIdx.x & 63;
    const float* rp = sup + (size_t)row * NN;
    int base = 0;
    for (int ch = 0; ch < NN / 64; ++ch) {
        float v = rp[ch * 64 + lane];
        unsigned long long m = __ballot(v != 0.0f);
        int pos = __popcll(m & ((1ull << lane) - 1ull));
        if (v != 0.0f) {
            int idx = base + pos;
            if (idx < MAXNNZ) {
                cols[row * MAXNNZ + idx] = ch * 64 + lane;
                vals[row * MAXNNZ + idx] = v;
            }
        }
        base += __popcll(m);
    }
    if (lane == 0) cnt[row] = base < MAXNNZ ? base : MAXNNZ;
}

// ---------------------------------------------------------------------------
// K2: build Xall (N x 4096) bf16: cols [0,2048) = inputs, [2048,4096) = hx
//     Xall[n][b*64+d]        = inputs[b][n*64+d]
//     Xall[n][2048+b*64+u]   = hx[b][n*64+u]
// fully coalesced reads (float4) and 8B writes.
// ---------------------------------------------------------------------------
__global__ void build_x0(const float* __restrict__ inp, const float* __restrict__ hxp,
                         unsigned short* __restrict__ Xall) {
    size_t tt = (size_t)blockIdx.x * 256 + threadIdx.x;
    size_t e  = tt * 4;                       // element index over 2*8388608
    int half  = e >= (size_t)8388608;
    size_t id = e & 8388607ull;               // b*262144 + n*64 + d
    const float* src = half ? hxp : inp;
    float4 f = *(const float4*)(src + id);
    int d = (int)(id & 63);
    int n = (int)((id >> 6) & 4095);
    int b = (int)(id >> 18);
    us4 o;
    o[0] = f2bf(f.x); o[1] = f2bf(f.y); o[2] = f2bf(f.z); o[3] = f2bf(f.w);
    *(us4*)(Xall + (size_t)n * 4096 + (size_t)half * 2048 + b * 64 + d) = o;
}

// ---------------------------------------------------------------------------
// K3: permute + transpose + bf16-cast weights.
// My feature order: f = m*128 + s  (m in 0..2, s in 0..127), original row s*3+m.
// Wt1[o][f] (o<128) from W_ru, Wt2[o][f] (o<64) from W_c.
// ---------------------------------------------------------------------------
__global__ void prep_w(const float* __restrict__ Wru, const float* __restrict__ Wc,
                       unsigned short* __restrict__ Wt1, unsigned short* __restrict__ Wt2) {
    int t = blockIdx.x * 256 + threadIdx.x;   // grid 288*256 = 73728 exactly
    if (t < 49152) {
        int o = t / 384, f = t - o * 384;
        int s = f & 127, m = f >> 7;
        Wt1[t] = f2bf(Wru[(s * 3 + m) * 128 + o]);
    } else {
        int u = t - 49152;
        int o = u / 384, f = u - o * 384;
        int s = f & 127, m = f >> 7;
        Wt2[u] = f2bf(Wc[(s * 3 + m) * 64 + o]);
    }
}

// ---------------------------------------------------------------------------
// SpMM: Y[row, c] = sum_k vals[row,k] * X[cols[row,k], c]   (per 256-col chunk)
// CHEB: Y = 2*(L@X) - Z0  (Chebyshev recursion step)
// One wave per (row, chunk); 4 cols/lane (8B loads). XCD-aware swizzle keeps
// each chunk's 2MB working set resident in one XCD's L2.
// ---------------------------------------------------------------------------
template <bool CHEB>
__global__ void spmm_kernel(const int* __restrict__ cols, const float* __restrict__ vals,
                            const int* __restrict__ cnt, const unsigned short* __restrict__ X,
                            const unsigned short* __restrict__ Z0,
                            unsigned short* __restrict__ Y, int ncols) {
    int T = gridDim.x;
    int fid = blockIdx.x;
    int v = (fid & 7) * (T >> 3) + (fid >> 3);   // XCD k owns v in [k*T/8,(k+1)*T/8)
    int chunk = v >> 10;                          // 1024 row-groups per chunk
    int rg = v & 1023;
    int row = rg * 4 + (threadIdx.x >> 6);
    int lane = threadIdx.x & 63;
    int c = chunk * 256 + lane * 4;
    const int* cp = cols + row * MAXNNZ;
    const float* vp = vals + row * MAXNNZ;
    int kc = cnt[row];
    float a0 = 0.f, a1 = 0.f, a2 = 0.f, a3 = 0.f;
    int k = 0;
    for (; k + 4 <= kc; k += 4) {
        int j0 = cp[k], j1 = cp[k + 1], j2 = cp[k + 2], j3 = cp[k + 3];
        float w0 = vp[k], w1 = vp[k + 1], w2 = vp[k + 2], w3 = vp[k + 3];
        us4 x0 = *(const us4*)(X + (size_t)j0 * ncols + c);
        us4 x1 = *(const us4*)(X + (size_t)j1 * ncols + c);
        us4 x2 = *(const us4*)(X + (size_t)j2 * ncols + c);
        us4 x3 = *(const us4*)(X + (size_t)j3 * ncols + c);
        a0 += w0 * bf2f(x0[0]) + w1 * bf2f(x1[0]) + w2 * bf2f(x2[0]) + w3 * bf2f(x3[0]);
        a1 += w0 * bf2f(x0[1]) + w1 * bf2f(x1[1]) + w2 * bf2f(x2[1]) + w3 * bf2f(x3[1]);
        a2 += w0 * bf2f(x0[2]) + w1 * bf2f(x1[2]) + w2 * bf2f(x2[2]) + w3 * bf2f(x3[2]);
        a3 += w0 * bf2f(x0[3]) + w1 * bf2f(x1[3]) + w2 * bf2f(x2[3]) + w3 * bf2f(x3[3]);
    }
    for (; k < kc; ++k) {
        int j = cp[k];
        float w = vp[k];
        us4 x = *(const us4*)(X + (size_t)j * ncols + c);
        a0 += w * bf2f(x[0]); a1 += w * bf2f(x[1]);
        a2 += w * bf2f(x[2]); a3 += w * bf2f(x[3]);
    }
    if (CHEB) {
        us4 z = *(const us4*)(Z0 + (size_t)row * ncols + c);
        a0 = 2.f * a0 - bf2f(z[0]); a1 = 2.f * a1 - bf2f(z[1]);
        a2 = 2.f * a2 - bf2f(z[2]); a3 = 2.f * a3 - bf2f(z[3]);
    }
    us4 o;
    o[0] = f2bf(a0); o[1] = f2bf(a1); o[2] = f2bf(a2); o[3] = f2bf(a3);
    *(us4*)(Y + (size_t)row * ncols + c) = o;
}

// ---------------------------------------------------------------------------
// Feature GEMM: C(128 rows x OC) = A(128 x 384) @ Wt^T, bf16 MFMA 16x16x32,
// fp32 accumulate. Rows = (b, n0..n0+127). Features f = m*128 + s, staged in
// 6 double-K-steps of 64 (one full 64-col region each: m x {inputs,state}).
// GATE epilogue: sigmoid -> write r*h (bf16, X2st) and u (f32, ubuf).
// FINAL epilogue: tanh -> out = u*h + (1-u)*c.
// ---------------------------------------------------------------------------
template <bool GATE>
__launch_bounds__(256)
__global__ void gemm_kernel(
    const unsigned short* __restrict__ in0, const unsigned short* __restrict__ in1,
    const unsigned short* __restrict__ in2,
    const unsigned short* __restrict__ st0, const unsigned short* __restrict__ st1,
    const unsigned short* __restrict__ st2, int stStride,
    const unsigned short* __restrict__ Wt, const float* __restrict__ bias,
    const float* __restrict__ hx, float* __restrict__ ubuf,
    unsigned short* __restrict__ x2st, float* __restrict__ outp) {
    constexpr int OC = GATE ? 128 : 64;
    constexpr int MF = GATE ? 8 : 4;
    __shared__ __align__(16) unsigned short A_lds[128 * 72];  // pad: 144B row stride
    __shared__ __align__(16) unsigned short W_lds[OC * 72];
    const int t = threadIdx.x;
    const int w = t >> 6, l = t & 63;
    const int bid = blockIdx.x;
    const int b = bid >> 5;            // 32 blocks of 128 rows per batch b
    const int n0 = (bid & 31) * 128;
    const int rowBaseW = GATE ? 0 : ((w >> 1) * 64);
    const int colBaseW = GATE ? (w * 32) : ((w & 1) * 32);
    f32x4 acc[MF][2];
#pragma unroll
    for (int i = 0; i < MF; ++i)
#pragma unroll
        for (int j = 0; j < 2; ++j)
#pragma unroll
            for (int r2 = 0; r2 < 4; ++r2) acc[i][j][r2] = 0.f;

#pragma unroll
    for (int kk2 = 0; kk2 < 6; ++kk2) {
        constexpr int dummy = 0; (void)dummy;
        const int m = kk2 >> 1;
        const bool stateReg = (kk2 & 1);
        const unsigned short* src =
            stateReg ? (m == 0 ? st0 : (m == 1 ? st1 : st2))
                     : (m == 0 ? in0 : (m == 1 ? in1 : in2));
        const int stride = stateReg ? stStride : NN;
        const int colb = b * 64;
        __syncthreads();
        {   // stage A: 128 rows x 64 bf16 (128B/row, 2 threads/row)
            int i = t >> 1;
            int ho = (t & 1) * 32;
            const unsigned short* s = src + (size_t)(n0 + i) * stride + colb + ho;
            us8 v0 = *(const us8*)(s);
            us8 v1 = *(const us8*)(s + 8);
            us8 v2 = *(const us8*)(s + 16);
            us8 v3 = *(const us8*)(s + 24);
            unsigned short* d = &A_lds[i * 72 + ho];
            *(us8*)(d) = v0; *(us8*)(d + 8) = v1;
            *(us8*)(d + 16) = v2; *(us8*)(d + 24) = v3;
        }
        {   // stage W: OC rows x 64 bf16
            int o = t >> 1;
            if (o < OC) {
                int ho = (t & 1) * 32;
                const unsigned short* s = Wt + o * 384 + kk2 * 64 + ho;
                us8 v0 = *(const us8*)(s);
                us8 v1 = *(const us8*)(s + 8);
                us8 v2 = *(const us8*)(s + 16);
                us8 v3 = *(const us8*)(s + 24);
                unsigned short* d = &W_lds[o * 72 + ho];
                *(us8*)(d) = v0; *(us8*)(d + 8) = v1;
                *(us8*)(d + 16) = v2; *(us8*)(d + 24) = v3;
            }
        }
        __syncthreads();
#pragma unroll
        for (int ss = 0; ss < 2; ++ss) {
            const int kb = ss * 32 + (l >> 4) * 8;
            bf16x8 bf0 = *(const bf16x8*)(&W_lds[(colBaseW + (l & 15)) * 72 + kb]);
            bf16x8 bf1 = *(const bf16x8*)(&W_lds[(colBaseW + 16 + (l & 15)) * 72 + kb]);
#pragma unroll
            for (int mf = 0; mf < MF; ++mf) {
                int r = rowBaseW + mf * 16 + (l & 15);
                bf16x8 a = *(const bf16x8*)(&A_lds[r * 72 + kb]);
                acc[mf][0] = __builtin_amdgcn_mfma_f32_16x16x32_bf16(a, bf0, acc[mf][0], 0, 0, 0);
                acc[mf][1] = __builtin_amdgcn_mfma_f32_16x16x32_bf16(a, bf1, acc[mf][1], 0, 0, 0);
            }
        }
    }
    // epilogue: D[(l>>4)*4 + rr][l&15] per 16x16 fragment
    const int l4 = (l >> 4) * 4;
    const int lc = l & 15;
    if (GATE) {
#pragma unroll
        for (int mf = 0; mf < MF; ++mf) {
#pragma unroll
            for (int nf = 0; nf < 2; ++nf) {
                int col = colBaseW + nf * 16 + lc;
#pragma unroll
                for (int rr = 0; rr < 4; ++rr) {
                    int nn = n0 + mf * 16 + l4 + rr;
                    float vv = acc[mf][nf][rr] + bias[col];
                    float s = 1.f / (1.f + __expf(-vv));
                    if (col < 64) {  // wave-uniform: waves 0,1 = r, waves 2,3 = u
                        float h = hx[(size_t)b * (NN * UU) + (size_t)nn * UU + col];
                        x2st[(size_t)nn * 2048 + b * 64 + col] = f2bf(s * h);
                    } else {
                        ubuf[(size_t)b * (NN * UU) + (size_t)nn * UU + (col - 64)] = s;
                    }
                }
            }
        }
    } else {
#pragma unroll
        for (int mf = 0; mf < MF; ++mf) {
#pragma unroll
            for (int nf = 0; nf < 2; ++nf) {
                int col = colBaseW + nf * 16 + lc;
#pragma unroll
                for (int rr = 0; rr < 4; ++rr) {
                    int nn = n0 + rowBaseW + mf * 16 + l4 + rr;
                    size_t idx = (size_t)b * (NN * UU) + (size_t)nn * UU + col;
                    float cc = tanhf(acc[mf][nf][rr] + bias[col]);
                    float u = ubuf[idx];
                    float h = hx[idx];
                    outp[idx] = u * h + (1.f - u) * cc;
                }
            }
        }
    }
}

// ---------------------------------------------------------------------------
extern "C" void kernel_launch(void* const* d_in, const int* in_sizes, int n_in,
                              void* d_out, int out_size, void* d_ws, size_t ws_size,
                              hipStream_t stream) {
    const float* inputs  = (const float*)d_in[0];
    const float* hx      = (const float*)d_in[1];
    const float* support = (const float*)d_in[2];
    const float* W_ru    = (const float*)d_in[3];
    const float* b_ru    = (const float*)d_in[4];
    const float* W_c     = (const float*)d_in[5];
    const float* b_c     = (const float*)d_in[6];
    float* out = (float*)d_out;

    char* ws = (char*)d_ws;
    size_t off = 0;
    auto alloc = [&](size_t bytes) -> char* {
        char* p = ws + off;
        off = (off + bytes + 255) & ~(size_t)255;
        return p;
    };
    int*            colsI = (int*)  alloc((size_t)NN * MAXNNZ * 4);
    float*          valsF = (float*)alloc((size_t)NN * MAXNNZ * 4);
    int*            cntI  = (int*)  alloc((size_t)NN * 4);
    unsigned short* Wt1   = (unsigned short*)alloc(128 * 384 * 2);
    unsigned short* Wt2   = (unsigned short*)alloc(64 * 384 * 2);
    unsigned short* Xall  = (unsigned short*)alloc((size_t)NN * 4096 * 2);
    unsigned short* Z1    = (unsigned short*)alloc((size_t)NN * 4096 * 2);
    unsigned short* Z2    = (unsigned short*)alloc((size_t)NN * 4096 * 2);
    unsigned short* X2st  = (unsigned short*)alloc((size_t)NN * 2048 * 2);
    unsigned short* Z1st  = (unsigned short*)alloc((size_t)NN * 2048 * 2);
    unsigned short* Z2st  = (unsigned short*)alloc((size_t)NN * 2048 * 2);
    float*          ubuf  = (float*)alloc((size_t)BB * NN * UU * 4);
    if (off > ws_size) return;  // workspace too small -> loud validation failure

    build_ell<<<1024, 256, 0, stream>>>(support, colsI, valsF, cntI);
    build_x0<<<16384, 256, 0, stream>>>(inputs, hx, Xall);
    prep_w<<<288, 256, 0, stream>>>(W_ru, W_c, Wt1, Wt2);

    // gconv1 diffusion over all 4096 columns
    spmm_kernel<false><<<16384, 256, 0, stream>>>(colsI, valsF, cntI, Xall, Xall, Z1, 4096);
    spmm_kernel<true><<<16384, 256, 0, stream>>>(colsI, valsF, cntI, Z1, Xall, Z2, 4096);
    // gate GEMM -> r*h (X2st) and u (ubuf)
    gemm_kernel<true><<<1024, 256, 0, stream>>>(Xall, Z1, Z2, Xall + 2048, Z1 + 2048,
                                                Z2 + 2048, 4096, Wt1, b_ru, hx, ubuf,
                                                X2st, nullptr);
    // gconv2 diffusion: only the 2048 state columns (inputs half reused from gconv1)
    spmm_kernel<false><<<8192, 256, 0, stream>>>(colsI, valsF, cntI, X2st, X2st, Z1st, 2048);
    spmm_kernel<true><<<8192, 256, 0, stream>>>(colsI, valsF, cntI, Z1st, X2st, Z2st, 2048);
    // candidate GEMM + GRU combine -> out
    gemm_kernel<false><<<1024, 256, 0, stream>>>(Xall, Z1, Z2, X2st, Z1st, Z2st, 2048,
                                                 Wt2, b_c, hx, ubuf, nullptr, out);
}

// Round 2
// 312.488 us; speedup vs baseline: 1.4404x; 1.4404x over previous
//
#include <hip/hip_runtime.h>

#define NN 4096
#define BB 32
#define UU 64
#define MAXNNZ 96

typedef float f32x4 __attribute__((ext_vector_type(4)));
typedef float f32x2 __attribute__((ext_vector_type(2)));
typedef short bf16x8 __attribute__((ext_vector_type(8)));
typedef unsigned short us8 __attribute__((ext_vector_type(8)));
typedef unsigned short us4 __attribute__((ext_vector_type(4)));

__device__ __forceinline__ float bf2f(unsigned short u) {
    return __uint_as_float(((unsigned)u) << 16);
}
__device__ __forceinline__ unsigned short f2bf(float f) {
    unsigned x = __float_as_uint(f);
    x += 0x7fffu + ((x >> 16) & 1u);
    return (unsigned short)(x >> 16);
}

// ---------------------------------------------------------------------------
// K1: dense support (4096x4096 f32) -> padded ELL (cols int32, vals f32, cnt)
// ---------------------------------------------------------------------------
__global__ void build_ell(const float* __restrict__ sup, int* __restrict__ cols,
                          float* __restrict__ vals, int* __restrict__ cnt) {
    int row  = blockIdx.x * 4 + (threadIdx.x >> 6);
    int lane = threadIdx.x & 63;
    const float* rp = sup + (size_t)row * NN;
    int base = 0;
    for (int ch = 0; ch < NN / 64; ++ch) {
        float v = rp[ch * 64 + lane];
        unsigned long long m = __ballot(v != 0.0f);
        int pos = __popcll(m & ((1ull << lane) - 1ull));
        if (v != 0.0f) {
            int idx = base + pos;
            if (idx < MAXNNZ) {
                cols[row * MAXNNZ + idx] = ch * 64 + lane;
                vals[row * MAXNNZ + idx] = v;
            }
        }
        base += __popcll(m);
    }
    if (lane == 0) cnt[row] = base < MAXNNZ ? base : MAXNNZ;
}

// ---------------------------------------------------------------------------
// K2: build Xall (N x 4096) bf16: cols [0,2048) = inputs, [2048,4096) = hx
// ---------------------------------------------------------------------------
__global__ void build_x0(const float* __restrict__ inp, const float* __restrict__ hxp,
                         unsigned short* __restrict__ Xall) {
    size_t tt = (size_t)blockIdx.x * 256 + threadIdx.x;
    size_t e  = tt * 4;
    int half  = e >= (size_t)8388608;
    size_t id = e & 8388607ull;               // b*262144 + n*64 + d
    const float* src = half ? hxp : inp;
    float4 f = *(const float4*)(src + id);
    int d = (int)(id & 63);
    int n = (int)((id >> 6) & 4095);
    int b = (int)(id >> 18);
    us4 o;
    o[0] = f2bf(f.x); o[1] = f2bf(f.y); o[2] = f2bf(f.z); o[3] = f2bf(f.w);
    *(us4*)(Xall + (size_t)n * 4096 + (size_t)half * 2048 + b * 64 + d) = o;
}

// ---------------------------------------------------------------------------
// K3: permute + transpose + bf16-cast weights.
// f = m*128 + s  (m in 0..2, s in 0..127), original row s*3+m.
// ---------------------------------------------------------------------------
__global__ void prep_w(const float* __restrict__ Wru, const float* __restrict__ Wc,
                       unsigned short* __restrict__ Wt1, unsigned short* __restrict__ Wt2) {
    int t = blockIdx.x * 256 + threadIdx.x;   // grid 288*256 = 73728 exactly
    if (t < 49152) {
        int o = t / 384, f = t - o * 384;
        int s = f & 127, m = f >> 7;
        Wt1[t] = f2bf(Wru[(s * 3 + m) * 128 + o]);
    } else {
        int u = t - 49152;
        int o = u / 384, f = u - o * 384;
        int s = f & 127, m = f >> 7;
        Wt2[u] = f2bf(Wc[(s * 3 + m) * 64 + o]);
    }
}

// ---------------------------------------------------------------------------
// SpMM: Y[row, c] = sum_k vals[row,k] * X[cols[row,k], c]
// CHEB: Y = 2*(L@X) - Z0
// One wave per (row, 512-col chunk); 8 cols/lane (16B gathers).
// Scalar-pipe loads for cols/vals/cnt (wave-uniform row via readfirstlane).
// XCD swizzle: each XCD owns one chunk (4MB X-slice resident in its L2).
// Non-temporal writes keep the gather working set in L2.
// ---------------------------------------------------------------------------
template <bool CHEB>
__launch_bounds__(256)
__global__ void spmm_kernel(const int* __restrict__ cols, const float* __restrict__ vals,
                            const int* __restrict__ cnt, const unsigned short* __restrict__ X,
                            const unsigned short* __restrict__ Z0,
                            unsigned short* __restrict__ Y, int ncols) {
    int T = gridDim.x;
    int fid = blockIdx.x;
    int v = (fid & 7) * (T >> 3) + (fid >> 3);   // XCD k owns v in [k*T/8,(k+1)*T/8)
    int chunk = v >> 10;                          // 1024 row-groups per chunk
    int rg = v & 1023;
    int row = __builtin_amdgcn_readfirstlane(rg * 4 + (threadIdx.x >> 6));
    int lane = threadIdx.x & 63;
    int c = chunk * 512 + lane * 8;
    const int* cp = cols + row * MAXNNZ;
    const float* vp = vals + row * MAXNNZ;
    int kc = cnt[row];
    f32x2 acc0 = {0.f, 0.f}, acc1 = {0.f, 0.f}, acc2 = {0.f, 0.f}, acc3 = {0.f, 0.f};
    int k = 0;
    for (; k + 4 <= kc; k += 4) {
        int j0 = cp[k], j1 = cp[k + 1], j2 = cp[k + 2], j3 = cp[k + 3];
        float s0 = vp[k], s1 = vp[k + 1], s2 = vp[k + 2], s3 = vp[k + 3];
        us8 x0 = *(const us8*)(X + (size_t)j0 * ncols + c);
        us8 x1 = *(const us8*)(X + (size_t)j1 * ncols + c);
        us8 x2 = *(const us8*)(X + (size_t)j2 * ncols + c);
        us8 x3 = *(const us8*)(X + (size_t)j3 * ncols + c);
        f32x2 w0 = {s0, s0}, w1 = {s1, s1}, w2 = {s2, s2}, w3 = {s3, s3};
        const unsigned* p0 = (const unsigned*)&x0;
        const unsigned* p1 = (const unsigned*)&x1;
        const unsigned* p2 = (const unsigned*)&x2;
        const unsigned* p3 = (const unsigned*)&x3;
#pragma unroll
        for (int i = 0; i < 4; ++i) {
            f32x2* ac = i == 0 ? &acc0 : (i == 1 ? &acc1 : (i == 2 ? &acc2 : &acc3));
            f32x2 xv;
            xv.x = __uint_as_float(p0[i] << 16); xv.y = __uint_as_float(p0[i] & 0xffff0000u);
            *ac = __builtin_elementwise_fma(w0, xv, *ac);
            xv.x = __uint_as_float(p1[i] << 16); xv.y = __uint_as_float(p1[i] & 0xffff0000u);
            *ac = __builtin_elementwise_fma(w1, xv, *ac);
            xv.x = __uint_as_float(p2[i] << 16); xv.y = __uint_as_float(p2[i] & 0xffff0000u);
            *ac = __builtin_elementwise_fma(w2, xv, *ac);
            xv.x = __uint_as_float(p3[i] << 16); xv.y = __uint_as_float(p3[i] & 0xffff0000u);
            *ac = __builtin_elementwise_fma(w3, xv, *ac);
        }
    }
    for (; k < kc; ++k) {
        int j = cp[k];
        float s = vp[k];
        f32x2 w = {s, s};
        us8 x = *(const us8*)(X + (size_t)j * ncols + c);
        const unsigned* p = (const unsigned*)&x;
#pragma unroll
        for (int i = 0; i < 4; ++i) {
            f32x2* ac = i == 0 ? &acc0 : (i == 1 ? &acc1 : (i == 2 ? &acc2 : &acc3));
            f32x2 xv;
            xv.x = __uint_as_float(p[i] << 16); xv.y = __uint_as_float(p[i] & 0xffff0000u);
            *ac = __builtin_elementwise_fma(w, xv, *ac);
        }
    }
    float a[8] = {acc0.x, acc0.y, acc1.x, acc1.y, acc2.x, acc2.y, acc3.x, acc3.y};
    if (CHEB) {
        us8 z = __builtin_nontemporal_load((const us8*)(Z0 + (size_t)row * ncols + c));
        const unsigned* pz = (const unsigned*)&z;
#pragma unroll
        for (int i = 0; i < 4; ++i) {
            a[2 * i]     = 2.f * a[2 * i]     - __uint_as_float(pz[i] << 16);
            a[2 * i + 1] = 2.f * a[2 * i + 1] - __uint_as_float(pz[i] & 0xffff0000u);
        }
    }
    us8 o;
#pragma unroll
    for (int i = 0; i < 8; ++i) o[i] = f2bf(a[i]);
    __builtin_nontemporal_store(o, (us8*)(Y + (size_t)row * ncols + c));
}

// ---------------------------------------------------------------------------
// Feature GEMM: C(128 rows x OC) = A(128 x 384) @ Wt^T, bf16 MFMA 16x16x32.
// GATE epilogue: sigmoid -> r*h (bf16, X2st) and u (bf16, ubuf).
// FINAL epilogue: tanh -> out = u*h + (1-u)*c.
// ---------------------------------------------------------------------------
template <bool GATE>
__launch_bounds__(256)
__global__ void gemm_kernel(
    const unsigned short* __restrict__ in0, const unsigned short* __restrict__ in1,
    const unsigned short* __restrict__ in2,
    const unsigned short* __restrict__ st0, const unsigned short* __restrict__ st1,
    const unsigned short* __restrict__ st2, int stStride,
    const unsigned short* __restrict__ Wt, const float* __restrict__ bias,
    const float* __restrict__ hx, unsigned short* __restrict__ ubuf,
    unsigned short* __restrict__ x2st, float* __restrict__ outp) {
    constexpr int OC = GATE ? 128 : 64;
    constexpr int MF = GATE ? 8 : 4;
    __shared__ __align__(16) unsigned short A_lds[128 * 72];  // pad: 144B row stride
    __shared__ __align__(16) unsigned short W_lds[OC * 72];
    const int t = threadIdx.x;
    const int w = t >> 6, l = t & 63;
    const int bid = blockIdx.x;
    const int b = bid >> 5;            // 32 blocks of 128 rows per batch b
    const int n0 = (bid & 31) * 128;
    const int rowBaseW = GATE ? 0 : ((w >> 1) * 64);
    const int colBaseW = GATE ? (w * 32) : ((w & 1) * 32);
    f32x4 acc[MF][2];
#pragma unroll
    for (int i = 0; i < MF; ++i)
#pragma unroll
        for (int j = 0; j < 2; ++j)
#pragma unroll
            for (int r2 = 0; r2 < 4; ++r2) acc[i][j][r2] = 0.f;

#pragma unroll
    for (int kk2 = 0; kk2 < 6; ++kk2) {
        const int m = kk2 >> 1;
        const bool stateReg = (kk2 & 1);
        const unsigned short* src =
            stateReg ? (m == 0 ? st0 : (m == 1 ? st1 : st2))
                     : (m == 0 ? in0 : (m == 1 ? in1 : in2));
        const int stride = stateReg ? stStride : NN;
        const int colb = b * 64;
        __syncthreads();
        {   // stage A: 128 rows x 64 bf16
            int i = t >> 1;
            int ho = (t & 1) * 32;
            const unsigned short* s = src + (size_t)(n0 + i) * stride + colb + ho;
            us8 v0 = *(const us8*)(s);
            us8 v1 = *(const us8*)(s + 8);
            us8 v2 = *(const us8*)(s + 16);
            us8 v3 = *(const us8*)(s + 24);
            unsigned short* d = &A_lds[i * 72 + ho];
            *(us8*)(d) = v0; *(us8*)(d + 8) = v1;
            *(us8*)(d + 16) = v2; *(us8*)(d + 24) = v3;
        }
        {   // stage W: OC rows x 64 bf16
            int o = t >> 1;
            if (o < OC) {
                int ho = (t & 1) * 32;
                const unsigned short* s = Wt + o * 384 + kk2 * 64 + ho;
                us8 v0 = *(const us8*)(s);
                us8 v1 = *(const us8*)(s + 8);
                us8 v2 = *(const us8*)(s + 16);
                us8 v3 = *(const us8*)(s + 24);
                unsigned short* d = &W_lds[o * 72 + ho];
                *(us8*)(d) = v0; *(us8*)(d + 8) = v1;
                *(us8*)(d + 16) = v2; *(us8*)(d + 24) = v3;
            }
        }
        __syncthreads();
#pragma unroll
        for (int ss = 0; ss < 2; ++ss) {
            const int kb = ss * 32 + (l >> 4) * 8;
            bf16x8 bf0 = *(const bf16x8*)(&W_lds[(colBaseW + (l & 15)) * 72 + kb]);
            bf16x8 bf1 = *(const bf16x8*)(&W_lds[(colBaseW + 16 + (l & 15)) * 72 + kb]);
#pragma unroll
            for (int mf = 0; mf < MF; ++mf) {
                int r = rowBaseW + mf * 16 + (l & 15);
                bf16x8 a = *(const bf16x8*)(&A_lds[r * 72 + kb]);
                acc[mf][0] = __builtin_amdgcn_mfma_f32_16x16x32_bf16(a, bf0, acc[mf][0], 0, 0, 0);
                acc[mf][1] = __builtin_amdgcn_mfma_f32_16x16x32_bf16(a, bf1, acc[mf][1], 0, 0, 0);
            }
        }
    }
    const int l4 = (l >> 4) * 4;
    const int lc = l & 15;
    if (GATE) {
#pragma unroll
        for (int mf = 0; mf < MF; ++mf) {
#pragma unroll
            for (int nf = 0; nf < 2; ++nf) {
                int col = colBaseW + nf * 16 + lc;
#pragma unroll
                for (int rr = 0; rr < 4; ++rr) {
                    int nn = n0 + mf * 16 + l4 + rr;
                    float vv = acc[mf][nf][rr] + bias[col];
                    float s = 1.f / (1.f + __expf(-vv));
                    if (col < 64) {  // wave-uniform: waves 0,1 = r, waves 2,3 = u
                        float h = hx[(size_t)b * (NN * UU) + (size_t)nn * UU + col];
                        x2st[(size_t)nn * 2048 + b * 64 + col] = f2bf(s * h);
                    } else {
                        ubuf[(size_t)b * (NN * UU) + (size_t)nn * UU + (col - 64)] = f2bf(s);
                    }
                }
            }
        }
    } else {
#pragma unroll
        for (int mf = 0; mf < MF; ++mf) {
#pragma unroll
            for (int nf = 0; nf < 2; ++nf) {
                int col = colBaseW + nf * 16 + lc;
#pragma unroll
                for (int rr = 0; rr < 4; ++rr) {
                    int nn = n0 + rowBaseW + mf * 16 + l4 + rr;
                    size_t idx = (size_t)b * (NN * UU) + (size_t)nn * UU + col;
                    float cc = tanhf(acc[mf][nf][rr] + bias[col]);
                    float u = bf2f(ubuf[idx]);
                    float h = hx[idx];
                    outp[idx] = u * h + (1.f - u) * cc;
                }
            }
        }
    }
}

// ---------------------------------------------------------------------------
extern "C" void kernel_launch(void* const* d_in, const int* in_sizes, int n_in,
                              void* d_out, int out_size, void* d_ws, size_t ws_size,
                              hipStream_t stream) {
    const float* inputs  = (const float*)d_in[0];
    const float* hx      = (const float*)d_in[1];
    const float* support = (const float*)d_in[2];
    const float* W_ru    = (const float*)d_in[3];
    const float* b_ru    = (const float*)d_in[4];
    const float* W_c     = (const float*)d_in[5];
    const float* b_c     = (const float*)d_in[6];
    float* out = (float*)d_out;

    char* ws = (char*)d_ws;
    size_t off = 0;
    auto alloc = [&](size_t bytes) -> char* {
        char* p = ws + off;
        off = (off + bytes + 255) & ~(size_t)255;
        return p;
    };
    int*            colsI = (int*)  alloc((size_t)NN * MAXNNZ * 4);
    float*          valsF = (float*)alloc((size_t)NN * MAXNNZ * 4);
    int*            cntI  = (int*)  alloc((size_t)NN * 4);
    unsigned short* Wt1   = (unsigned short*)alloc(128 * 384 * 2);
    unsigned short* Wt2   = (unsigned short*)alloc(64 * 384 * 2);
    unsigned short* Xall  = (unsigned short*)alloc((size_t)NN * 4096 * 2);
    unsigned short* Z1    = (unsigned short*)alloc((size_t)NN * 4096 * 2);
    unsigned short* Z2    = (unsigned short*)alloc((size_t)NN * 4096 * 2);
    unsigned short* X2st  = (unsigned short*)alloc((size_t)NN * 2048 * 2);
    unsigned short* Z1st  = (unsigned short*)alloc((size_t)NN * 2048 * 2);
    unsigned short* Z2st  = (unsigned short*)alloc((size_t)NN * 2048 * 2);
    unsigned short* ubuf  = (unsigned short*)alloc((size_t)BB * NN * UU * 2);
    if (off > ws_size) return;  // workspace too small -> loud validation failure

    build_ell<<<1024, 256, 0, stream>>>(support, colsI, valsF, cntI);
    build_x0<<<16384, 256, 0, stream>>>(inputs, hx, Xall);
    prep_w<<<288, 256, 0, stream>>>(W_ru, W_c, Wt1, Wt2);

    // gconv1 diffusion over all 4096 columns (8 chunks of 512)
    spmm_kernel<false><<<8192, 256, 0, stream>>>(colsI, valsF, cntI, Xall, Xall, Z1, 4096);
    spmm_kernel<true><<<8192, 256, 0, stream>>>(colsI, valsF, cntI, Z1, Xall, Z2, 4096);
    // gate GEMM -> r*h (X2st) and u (ubuf)
    gemm_kernel<true><<<1024, 256, 0, stream>>>(Xall, Z1, Z2, Xall + 2048, Z1 + 2048,
                                                Z2 + 2048, 4096, Wt1, b_ru, hx, ubuf,
                                                X2st, nullptr);
    // gconv2 diffusion: only the 2048 state columns (4 chunks of 512)
    spmm_kernel<false><<<4096, 256, 0, stream>>>(colsI, valsF, cntI, X2st, X2st, Z1st, 2048);
    spmm_kernel<true><<<4096, 256, 0, stream>>>(colsI, valsF, cntI, Z1st, X2st, Z2st, 2048);
    // candidate GEMM + GRU combine -> out
    gemm_kernel<false><<<1024, 256, 0, stream>>>(Xall, Z1, Z2, X2st, Z1st, Z2st, 2048,
                                                 Wt2, b_c, hx, ubuf, nullptr, out);
}